// Round 6
// baseline (206.869 us; speedup 1.0000x reference)
//
#include <hip/hip_runtime.h>
#include <hip/hip_fp16.h>
#include <math.h>

#define NLOR  65536
#define NG    128
#define PLANE (NG * NG)
#define NSUB  2
#define KG    8               /* planes per proj block */
#define NKG   (NG / KG)       /* 16 plane groups */

#define VOX    1.671875f                 /* 214/128 exact */
#define XMIN  (-107.0f)
/* weight arg in cell units: (pi/2)(m+d)^2 ; C2L = (pi/2)*log2(e) */
#define C2     1.57079632679f
#define C2L    2.26618007f

#define FPSCALE    8388608.0f            /* 2^23 fixed-point scale */
#define INVFPSCALE (1.0f / 8388608.0f)

/* padded LDS accumulator stride (bp) */
#define PLP    129

// Per-LOR precomputed affine params, 8 floats:
//   [0]=u0 [1]=du [2]=v0 [3]=dv   (y-family stored pre-swapped)
//   [4]=t0 [5]=dt [6]=cf*2^23 (filled by reduce_cf3) [7]=pad
#define PRM_STRIDE 8

typedef _Float16 h2v __attribute__((ext_vector_type(2)));

#if defined(__has_builtin)
#if __has_builtin(__builtin_amdgcn_fdot2)
#define HAVE_FDOT2 1
#endif
#endif

__device__ __forceinline__ float fdot2w(unsigned w, h2v wt, float c)
{
#ifdef HAVE_FDOT2
    return __builtin_amdgcn_fdot2(__builtin_bit_cast(h2v, w), wt, c, false);
#else
    const __half2 h = *reinterpret_cast<const __half2*>(&w);
    const float2 f = __half22float2(h);
    return c + (float)wt.x * f.x + (float)wt.y * f.y;
#endif
}

// ---------------------------------------------------------------------------
// Tiled 3D permute body for the half-precision staged image volumes.
// ---------------------------------------------------------------------------
template<int SP, int SQ, int SR, int CONTIG>
__device__ __forceinline__ void permute_half_body(
    const float* __restrict__ in, __half* __restrict__ out,
    int b, float (*tile)[33])
{
    const int c0 = blockIdx.x * 32;
    const int r0 = blockIdx.y * 32;
    const int tx = threadIdx.x, ty = threadIdx.y;

#pragma unroll
    for (int m = 0; m < 4; ++m) {
        const int C = c0 + tx;
        const int R = r0 + ty + 8 * m;
        const int P = (CONTIG == 0) ? C : b;
        const int Q = (CONTIG == 0) ? b : C;
        tile[ty + 8 * m][tx] = in[P * SP + Q * SQ + R * SR];
    }
    __syncthreads();
#pragma unroll
    for (int m = 0; m < 4; ++m) {
        const int R = r0 + tx;
        const int C = c0 + ty + 8 * m;
        const int P = (CONTIG == 0) ? C : b;
        const int Q = (CONTIG == 0) ? b : C;
        const int o = P * PLANE + Q * NG + R;
        out[o] = __float2half(tile[tx][ty + 8 * m]);
    }
}

// ---------------------------------------------------------------------------
// Fused: both image permutes + per-LOR affine param precompute.
// b<128 -> imgPz [z][x][y]; b<256 -> imgPx [y][z][x]; b>=256 -> lor_prep
// (48 slices x 16 xy-blocks x 256 thr = 196608 = 3 x 65536 LORs).
// ---------------------------------------------------------------------------
__global__ __launch_bounds__(256)
void perm_img2(const float* __restrict__ image,
               __half* __restrict__ imgPz, __half* __restrict__ imgPx,
               const float* __restrict__ zl, const float* __restrict__ yl,
               const float* __restrict__ xl,
               float* __restrict__ prmz, float* __restrict__ prmy,
               float* __restrict__ prmx)
{
    __shared__ float tile[32][33];
    const int b = blockIdx.z;
    if (b < 128) {
        permute_half_body<1, 16384, 128, 0>(image, imgPz, b, tile);
        return;
    }
    if (b < 256) {
        permute_half_body<128, 1, 16384, 1>(image, imgPx, b - 128, tile);
        return;
    }
    // ---- LOR prep ----
    const int linear = (b - 256) * 16 + blockIdx.y * 4 + blockIdx.x;
    const int gid = linear * 256 + threadIdx.y * 32 + threadIdx.x;
    const int f   = gid >> 16;              /* family: uniform per block */
    const int lor = gid & (NLOR - 1);
    const float* lors = (f == 0) ? zl : (f == 1) ? yl : xl;
    float* prm        = (f == 0) ? prmz : (f == 1) ? prmy : prmx;

    const float p1x = lors[0 * NLOR + lor];
    const float p1y = lors[1 * NLOR + lor];
    const float p1z = lors[2 * NLOR + lor];
    const float dx  = lors[3 * NLOR + lor] - p1x;
    const float dy  = lors[4 * NLOR + lor] - p1y;
    float dz = lors[5 * NLOR + lor] - p1z;
    dz = (fabsf(dz) < 1e-6f) ? 1e-6f : dz;
    const float rdz = 1.0f / dz;

    const float t0 = (XMIN + 0.5f * VOX - p1z) * rdz;   /* t at plane k=0 */
    const float dt = VOX * rdz;
    float u0 = (fmaf(t0, dx, p1x) - XMIN) * (1.0f / VOX) - 0.5f;
    float v0 = (fmaf(t0, dy, p1y) - XMIN) * (1.0f / VOX) - 0.5f;
    float du = dx * rdz;
    float dv = dy * rdz;
    if (f == 1) {   /* y-family consumes the z-permuted volume with axes swapped */
        float tmp = u0; u0 = v0; v0 = tmp;
        tmp = du; du = dv; dv = tmp;
    }
    float4* p4 = (float4*)(prm + (size_t)lor * PRM_STRIDE);
    p4[0] = make_float4(u0, du, v0, dv);
    p4[1] = make_float4(t0, dt, 0.0f, 0.0f);
}

// ---------------------------------------------------------------------------
// Projection. Plane staged in LDS as TWO shifted half2 copies (64 KB):
//   plE word m = cols (2m, 2m+1); plO word m = cols (2m+1, 2m+2).
// Any 3-voxel window [j0-1 .. j0+1] = words w,w+1 of the parity-selected
// copy with uniform weight layout (eym,ey0 | eyq,0) -> no odd/even selects,
// gather via v_dot2_f32_f16 (2 dot2 + 1 fma per row vs 4 cvt + 5 fma).
// blockIdx.x = plane group (XCD selector). blockIdx.y = chunk.
// ---------------------------------------------------------------------------
template<int NS>
__device__ __forceinline__ void proj_body(
    const float* const* prmv, const unsigned int* __restrict__ imgP,
    float* const* p8v, unsigned int* plE, unsigned int* plO)
{
    const int g     = blockIdx.x;          // 16 plane groups (XCD selector)
    const int chunk = blockIdx.y;          // 32 chunks x 2048 LORs
    const int tid   = threadIdx.x;
    const int lor0  = chunk * 2048 + tid;
    const float k0  = (float)(g * KG);

    float tA[2 * NS], uA[2 * NS], vA[2 * NS], dtA[2 * NS], duA[2 * NS], dvA[2 * NS], sA[2 * NS];
#pragma unroll
    for (int s = 0; s < 2 * NS; ++s) {
        const float* prm = prmv[s >> 1];
        const int lor = lor0 + (s & 1) * 1024;
        const float4* p4 = (const float4*)(prm + (size_t)lor * PRM_STRIDE);
        const float4 a = p4[0];
        const float4 b = p4[1];
        tA[s] = fmaf(k0, b.y, b.x);  dtA[s] = b.y;
        uA[s] = fmaf(k0, a.y, a.x);  duA[s] = a.y;
        vA[s] = fmaf(k0, a.w, a.z);  dvA[s] = a.w;
        sA[s] = 0.0f;
    }

    for (int st = 0; st < KG; ++st) {
        const int k = g * KG + st;
        const unsigned* srcw = imgP + k * (NG * 64);
        const uint4* src = (const uint4*)srcw;
        uint4* dstE = (uint4*)plE;
        uint4* dstO = (uint4*)plO;
        for (int i = tid; i < (NG * 64) / 4; i += 1024) {
            const uint4 a = src[i];
            /* one word past the 4 loaded: only feeds never-read row-end word;
               address stays inside the workspace even for the last plane */
            const unsigned nxt = srcw[4 * i + 4];
            uint4 o;
            o.x = (a.x >> 16) | (a.y << 16);
            o.y = (a.y >> 16) | (a.z << 16);
            o.z = (a.z >> 16) | (a.w << 16);
            o.w = (a.w >> 16) | (nxt << 16);
            dstE[i] = a;
            dstO[i] = o;
        }
        __syncthreads();

        const float fst = (float)st;
#pragma unroll
        for (int s = 0; s < 2 * NS; ++s) {
            const float t = fmaf(fst, dtA[s], tA[s]);
            const float u = fmaf(fst, duA[s], uA[s]);
            const float v = fmaf(fst, dvA[s], vA[s]);
            const float fi = rintf(u);
            const float fj = rintf(v);
            const int i0 = (int)fi;
            const int j0 = (int)fj;
            const float mi = fi - u;
            const float mj = fj - v;
            const float ci = -C2L * mi,  cj = -C2L * mj;
            const float a0i = ci * mi,   a0j = cj * mj;
            const float gi = ci + ci,    gj = cj + cj;
            const float ki = a0i - C2L,  kj = a0j - C2L;
            const float exm = __builtin_amdgcn_exp2f(ki - gi);
            const float ex0 = __builtin_amdgcn_exp2f(a0i);
            const float exq = __builtin_amdgcn_exp2f(ki + gi);
            const float eym = __builtin_amdgcn_exp2f(kj - gj);
            const float ey0 = __builtin_amdgcn_exp2f(a0j);
            const float eyq = __builtin_amdgcn_exp2f(kj + gj);

            h2v wLo; wLo.x = (_Float16)eym; wLo.y = (_Float16)ey0;
            h2v wHi; wHi.x = (_Float16)eyq; wHi.y = (_Float16)0.0f;

            const int w  = min(max((j0 - 1) >> 1, 0), 62);
            const int ib = min(max(i0 - 1, 0), 125);
            const unsigned* pp = (j0 & 1) ? plE : plO;

            const float exv[3] = {exm, ex0, exq};
            float acc = 0.0f;
#pragma unroll
            for (int a = 0; a < 3; ++a) {
                const int rowb = (ib + a) << 6;
                const unsigned Aw = pp[rowb + w];
                const unsigned Bw = pp[rowb + w + 1];
                float rd = fdot2w(Bw, wHi, 0.0f);
                rd = fdot2w(Aw, wLo, rd);
                acc = fmaf(exv[a], rd, acc);
            }
            const bool tin = (t >= 0.0f) && (t <= 1.0f);
            sA[s] += tin ? acc : 0.0f;
        }
        __syncthreads();
    }
#pragma unroll
    for (int s = 0; s < NS; ++s) {
        p8v[s][g * NLOR + lor0]        = sA[2 * s];
        p8v[s][g * NLOR + lor0 + 1024] = sA[2 * s + 1];
    }
}

// blockIdx.z==0: z+y streams on imgPz; ==1: x stream on imgPx.
__global__ __launch_bounds__(1024, 8)
void proj_all(const float* __restrict__ prmz, const float* __restrict__ prmy,
              const float* __restrict__ prmx,
              const unsigned int* __restrict__ imgPz, const unsigned int* __restrict__ imgPx,
              float* __restrict__ p8z, float* __restrict__ p8y,
              float* __restrict__ p8x)
{
    __shared__ unsigned int plE[NG * 64];    /* 32 KB: cols (2m, 2m+1)   */
    __shared__ unsigned int plO[NG * 64];    /* 32 KB: cols (2m+1, 2m+2) */
    if (blockIdx.z == 0) {
        const float* prmv[2] = {prmz, prmy};
        float* p8v[2] = {p8z, p8y};
        proj_body<2>(prmv, imgPz, p8v, plE, plO);
    } else {
        const float* prmv[1] = {prmx};
        float* p8v[1] = {p8x};
        proj_body<1>(prmv, imgPx, p8v, plE, plO);
    }
}

// ---------------------------------------------------------------------------
// cf for all three passes in one dispatch (blockIdx.y selects the pass).
// Stores cf PRE-SCALED by 2^23 into slot 6 (saves a mul per bp deposit).
// ---------------------------------------------------------------------------
__global__ __launch_bounds__(256)
void reduce_cf3(const float* __restrict__ zl, const float* __restrict__ yl,
                const float* __restrict__ xl,
                const float* __restrict__ p8z, const float* __restrict__ p8y,
                const float* __restrict__ p8x,
                float* __restrict__ prmz, float* __restrict__ prmy,
                float* __restrict__ prmx)
{
    const int which = blockIdx.y;
    const float* lors  = (which == 0) ? zl  : (which == 1) ? yl  : xl;
    const float* part8 = (which == 0) ? p8z : (which == 1) ? p8y : p8x;
    float*       prm   = (which == 0) ? prmz : (which == 1) ? prmy : prmx;

    const int lor = blockIdx.x * 256 + threadIdx.x;
    float s = 0.0f;
#pragma unroll
    for (int g = 0; g < NKG; ++g) s += part8[g * NLOR + lor];

    const float p1x = lors[0 * NLOR + lor];
    const float p1y = lors[1 * NLOR + lor];
    const float p1z = lors[2 * NLOR + lor];
    const float dx  = lors[3 * NLOR + lor] - p1x;
    const float dy  = lors[4 * NLOR + lor] - p1y;
    const float dz0 = lors[5 * NLOR + lor] - p1z;
    const float L = sqrtf(dx * dx + dy * dy + dz0 * dz0);
    const float adz = fmaxf(fabsf(dz0), 1e-6f);
    const float dl = VOX * L / adz;
    prm[(size_t)lor * PRM_STRIDE + 6] = (dl / (s * dl + 1e-8f)) * FPSCALE;
}

// ---------------------------------------------------------------------------
// bp deposit, op-minimized: exp2-domain weight recurrence, float-domain med3
// clamp + single fma address, select instead of branch, pre-scaled cf.
// u32 fixed-point LDS atomics (fp32 LDS atomics ~10x slower on gfx950).
// ---------------------------------------------------------------------------
__device__ __forceinline__ void bp_deposit(const float* __restrict__ prm,
    int lor, float fk, unsigned int* __restrict__ pl)
{
    const float4* p4 = (const float4*)(prm + (size_t)lor * PRM_STRIDE);
    const float4 a = p4[0];
    const float4 b = p4[1];
    const float t = fmaf(fk, b.y, b.x);
    const float u = fmaf(fk, a.y, a.x);
    const float v = fmaf(fk, a.w, a.z);
    const float fi = rintf(u);
    const float fj = rintf(v);
    const float cfs = ((t >= 0.0f) && (t <= 1.0f)) ? b.z : 0.0f;  /* cf*2^23 */

    const float mi = fi - u;
    const float mj = fj - v;
    const float ci = -C2L * mi,  cj = -C2L * mj;
    const float a0i = ci * mi,   a0j = cj * mj;
    const float gi = ci + ci,    gj = cj + cj;
    const float ki = a0i - C2L,  kj = a0j - C2L;

    const float ex0 = __builtin_amdgcn_exp2f(a0i) * cfs;
    const float exm = __builtin_amdgcn_exp2f(ki - gi) * cfs;
    const float exq = __builtin_amdgcn_exp2f(ki + gi) * cfs;
    const float ey0 = __builtin_amdgcn_exp2f(a0j);
    const float eym = __builtin_amdgcn_exp2f(kj - gj);
    const float eyq = __builtin_amdgcn_exp2f(kj + gj);

    /* clamp in float, one fma -> flat index; 9 targets = imm ds offsets */
    const float fib = __builtin_amdgcn_fmed3f(fi, 1.0f, 126.0f);
    const float fjb = __builtin_amdgcn_fmed3f(fj, 1.0f, 126.0f);
    const int idx = (int)fmaf(fib, (float)PLP, fjb) - (PLP + 1);
    unsigned int* base = pl + idx;

    const float exv[3] = {exm, ex0, exq};
#pragma unroll
    for (int aa = 0; aa < 3; ++aa) {
        unsigned int* row = base + aa * PLP;
        atomicAdd(row + 0, (unsigned int)(exv[aa] * eym));
        atomicAdd(row + 1, (unsigned int)(exv[aa] * ey0));
        atomicAdd(row + 2, (unsigned int)(exv[aa] * eyq));
    }
}

// ---------------------------------------------------------------------------
// All backprojection in one launch. blockIdx.y==0: z+y -> bpA; ==1: x -> bpB.
// Writes planes TRANSPOSED: bpA = A'[s][z][y][x], bpB = B'[s][y][x][z].
// ---------------------------------------------------------------------------
__global__ __launch_bounds__(1024)
void bp_all(const float* __restrict__ prmz, const float* __restrict__ prmy,
            const float* __restrict__ prmx,
            float* __restrict__ bpA, float* __restrict__ bpB)
{
    __shared__ unsigned int pl[NG * PLP];      /* 64.5 KB padded u32 plane */
    const int k   = blockIdx.x >> 1;
    const int sub = blockIdx.x & 1;
    const int tid = threadIdx.x;

    for (int i = tid; i < NG * PLP; i += 1024) pl[i] = 0u;
    __syncthreads();

    const float fk = (float)k;
    const int lo = sub * (NLOR / NSUB);
    constexpr int NIT = (NLOR / NSUB) / 1024;   /* 32 */
    float* bpsub;
    if (blockIdx.y == 0) {
#pragma unroll 2
        for (int it = 0; it < NIT; ++it) {
            const int lor = lo + tid + it * 1024;
            bp_deposit(prmz, lor, fk, pl);
            bp_deposit(prmy, lor, fk, pl);
        }
        bpsub = bpA;
    } else {
#pragma unroll 4
        for (int it = 0; it < NIT; ++it)
            bp_deposit(prmx, lo + tid + it * 1024, fk, pl);
        bpsub = bpB;
    }
    __syncthreads();

    /* transposed writeout: dst[q*128 + p] = pl[p][q]; LDS lanes stride PLP
       (conflict-free), global contiguous */
    float* dst = bpsub + ((size_t)(sub * NG + k)) * PLANE;
    for (int idx = tid; idx < PLANE; idx += 1024)
        dst[idx] = (float)pl[(idx & 127) * PLP + (idx >> 7)] * INVFPSCALE;
}

// ---------------------------------------------------------------------------
// Single-pass finalize: out[x][y][z] = img/eff * (sum_s A'[s][z][y][x]
//                                              +  sum_s B'[s][y][x][z]).
// ---------------------------------------------------------------------------
__global__ __launch_bounds__(256)
void finalize_out(const float* __restrict__ bpA, const float* __restrict__ bpB,
                  const float* __restrict__ img, const float* __restrict__ eff,
                  float* __restrict__ out)
{
    __shared__ float tA[32][33];
    const int b  = blockIdx.z;              /* y */
    const int x0 = blockIdx.x * 32;
    const int z0 = blockIdx.y * 32;
    const int tx = threadIdx.x, ty = threadIdx.y;
    const int VOL = NG * PLANE;

#pragma unroll
    for (int m = 0; m < 4; ++m) {
        const int z = z0 + ty + 8 * m;
        const int a = z * PLANE + b * NG + (x0 + tx);
        tA[ty + 8 * m][tx] = bpA[a] + bpA[a + VOL];
    }
    __syncthreads();
#pragma unroll
    for (int m = 0; m < 4; ++m) {
        const int x  = x0 + ty + 8 * m;
        const int o  = x * PLANE + b * NG + (z0 + tx);
        const int bb = b * PLANE + x * NG + (z0 + tx);
        const float v = tA[tx][ty + 8 * m] + bpB[bb] + bpB[bb + VOL];
        out[o] = img[o] / (eff[o] + 1e-8f) * v;
    }
}

extern "C" void kernel_launch(void* const* d_in, const int* in_sizes, int n_in,
                              void* d_out, int out_size, void* d_ws, size_t ws_size,
                              hipStream_t stream) {
    const float* image = (const float*)d_in[0];
    const float* eff   = (const float*)d_in[1];
    const float* xl    = (const float*)d_in[2];
    const float* yl    = (const float*)d_in[3];
    const float* zl    = (const float*)d_in[4];
    float* out = (float*)d_out;

    char* ws = (char*)d_ws;
    __half* imgPz = (__half*)(ws);                       //  4 MB [z][x][y] half
    __half* imgPx = (__half*)(ws + (size_t)( 4 << 20));  //  4 MB [y][z][x] half
    float* bpA    = (float*)(ws + (size_t)( 8 << 20));   // 16 MB A'[s][z][y][x]
    float* bpB    = (float*)(ws + (size_t)(24 << 20));   // 16 MB B'[s][y][x][z]
    float* p8z    = (float*)(ws + (size_t)(40 << 20));   //  4 MB
    float* p8y    = (float*)(ws + (size_t)(44 << 20));   //  4 MB
    float* p8x    = (float*)(ws + (size_t)(48 << 20));   //  4 MB
    float* prmz   = (float*)(ws + (size_t)(52 << 20));   //  2 MB per-LOR params
    float* prmy   = (float*)(ws + (size_t)(54 << 20));   //  2 MB
    float* prmx   = (float*)(ws + (size_t)(56 << 20));   //  2 MB

    const dim3 tb(32, 8);

    // 1) image permutes + LOR param prep, one launch (z slices 256..303 = prep)
    perm_img2<<<dim3(4, 4, 304), tb, 0, stream>>>(image, imgPz, imgPx,
        zl, yl, xl, prmz, prmy, prmx);
    // 2) all projections; grid.x = plane group for XCD L2 locality
    proj_all<<<dim3(16, 32, 2), 1024, 0, stream>>>(prmz, prmy, prmx,
        (const unsigned int*)imgPz, (const unsigned int*)imgPx, p8z, p8y, p8x);
    // 3) correction factors (pre-scaled by 2^23) -> params slot 6
    reduce_cf3<<<dim3(256, 3), 256, 0, stream>>>(zl, yl, xl, p8z, p8y, p8x, prmz, prmy, prmx);
    // 4) all backprojection (z+y -> bpA | x -> bpB), transposed plane writeout
    bp_all<<<dim3(128 * NSUB, 2), 1024, 0, stream>>>(prmz, prmy, prmx, bpA, bpB);
    // 5) fused gather + finalize (single pass over out)
    finalize_out<<<dim3(4, 4, 128), tb, 0, stream>>>(bpA, bpB, image, eff, out);
}

// Round 7
// 195.251 us; speedup vs baseline: 1.0595x; 1.0595x over previous
//
#include <hip/hip_runtime.h>
#include <hip/hip_fp16.h>
#include <math.h>

#define NLOR  65536
#define NG    128
#define PLANE (NG * NG)
#define NSUB  2
#define KG    8               /* planes per proj block */
#define NKG   (NG / KG)       /* 16 plane groups */

#define VOX    1.671875f                 /* 214/128 exact */
#define XMIN  (-107.0f)
/* weight arg in cell units: (pi/2)(m+d)^2 ; C2L = (pi/2)*log2(e) */
#define C2     1.57079632679f
#define C2L    2.26618007f

#define FPSCALE    8388608.0f            /* 2^23 fixed-point scale */
#define INVFPSCALE (1.0f / 8388608.0f)

/* padded LDS accumulator stride (bp) */
#define PLP    129

// Per-LOR precomputed affine params, 8 floats:
//   [0]=u0 [1]=du [2]=v0 [3]=dv   (y-family stored pre-swapped)
//   [4]=t0 [5]=dt [6]=cf*2^23 (filled by reduce_cf3) [7]=pad
#define PRM_STRIDE 8

typedef _Float16 h2v __attribute__((ext_vector_type(2)));

#if defined(__has_builtin)
#if __has_builtin(__builtin_amdgcn_fdot2)
#define HAVE_FDOT2 1
#endif
#endif

__device__ __forceinline__ float fdot2w(unsigned w, h2v wt, float c)
{
#ifdef HAVE_FDOT2
    return __builtin_amdgcn_fdot2(__builtin_bit_cast(h2v, w), wt, c, false);
#else
    const __half2 h = *reinterpret_cast<const __half2*>(&w);
    const float2 f = __half22float2(h);
    return c + (float)wt.x * f.x + (float)wt.y * f.y;
#endif
}

// ---------------------------------------------------------------------------
// Tiled 3D permute body for the half-precision staged image volumes.
// ---------------------------------------------------------------------------
template<int SP, int SQ, int SR, int CONTIG>
__device__ __forceinline__ void permute_half_body(
    const float* __restrict__ in, __half* __restrict__ out,
    int b, float (*tile)[33])
{
    const int c0 = blockIdx.x * 32;
    const int r0 = blockIdx.y * 32;
    const int tx = threadIdx.x, ty = threadIdx.y;

#pragma unroll
    for (int m = 0; m < 4; ++m) {
        const int C = c0 + tx;
        const int R = r0 + ty + 8 * m;
        const int P = (CONTIG == 0) ? C : b;
        const int Q = (CONTIG == 0) ? b : C;
        tile[ty + 8 * m][tx] = in[P * SP + Q * SQ + R * SR];
    }
    __syncthreads();
#pragma unroll
    for (int m = 0; m < 4; ++m) {
        const int R = r0 + tx;
        const int C = c0 + ty + 8 * m;
        const int P = (CONTIG == 0) ? C : b;
        const int Q = (CONTIG == 0) ? b : C;
        const int o = P * PLANE + Q * NG + R;
        out[o] = __float2half(tile[tx][ty + 8 * m]);
    }
}

// ---------------------------------------------------------------------------
// Fused: both image permutes + per-LOR affine param precompute.
// b<128 -> imgPz [z][x][y]; b<256 -> imgPx [y][z][x]; b>=256 -> lor_prep
// (48 slices x 16 xy-blocks x 256 thr = 196608 = 3 x 65536 LORs).
// ---------------------------------------------------------------------------
__global__ __launch_bounds__(256)
void perm_img2(const float* __restrict__ image,
               __half* __restrict__ imgPz, __half* __restrict__ imgPx,
               const float* __restrict__ zl, const float* __restrict__ yl,
               const float* __restrict__ xl,
               float* __restrict__ prmz, float* __restrict__ prmy,
               float* __restrict__ prmx)
{
    __shared__ float tile[32][33];
    const int b = blockIdx.z;
    if (b < 128) {
        permute_half_body<1, 16384, 128, 0>(image, imgPz, b, tile);
        return;
    }
    if (b < 256) {
        permute_half_body<128, 1, 16384, 1>(image, imgPx, b - 128, tile);
        return;
    }
    // ---- LOR prep ----
    const int linear = (b - 256) * 16 + blockIdx.y * 4 + blockIdx.x;
    const int gid = linear * 256 + threadIdx.y * 32 + threadIdx.x;
    const int f   = gid >> 16;              /* family: uniform per block */
    const int lor = gid & (NLOR - 1);
    const float* lors = (f == 0) ? zl : (f == 1) ? yl : xl;
    float* prm        = (f == 0) ? prmz : (f == 1) ? prmy : prmx;

    const float p1x = lors[0 * NLOR + lor];
    const float p1y = lors[1 * NLOR + lor];
    const float p1z = lors[2 * NLOR + lor];
    const float dx  = lors[3 * NLOR + lor] - p1x;
    const float dy  = lors[4 * NLOR + lor] - p1y;
    float dz = lors[5 * NLOR + lor] - p1z;
    dz = (fabsf(dz) < 1e-6f) ? 1e-6f : dz;
    const float rdz = 1.0f / dz;

    const float t0 = (XMIN + 0.5f * VOX - p1z) * rdz;   /* t at plane k=0 */
    const float dt = VOX * rdz;
    float u0 = (fmaf(t0, dx, p1x) - XMIN) * (1.0f / VOX) - 0.5f;
    float v0 = (fmaf(t0, dy, p1y) - XMIN) * (1.0f / VOX) - 0.5f;
    float du = dx * rdz;
    float dv = dy * rdz;
    if (f == 1) {   /* y-family consumes the z-permuted volume with axes swapped */
        float tmp = u0; u0 = v0; v0 = tmp;
        tmp = du; du = dv; dv = tmp;
    }
    float4* p4 = (float4*)(prm + (size_t)lor * PRM_STRIDE);
    p4[0] = make_float4(u0, du, v0, dv);
    p4[1] = make_float4(t0, dt, 0.0f, 0.0f);
}

// ---------------------------------------------------------------------------
// Projection. Plane staged in LDS as half2 pairs (32 KB, single copy).
// Register-prefetch pipeline (T14 async-split): stage st+1's global loads
// are issued BEFORE computing stage st, so HBM/L2 latency hides under the
// compute phase instead of sitting between the two barriers (round-6
// post-mortem: exposed staging latency, not VALU, is the idle).
// Gather via v_dot2_f32_f16 with parity-selected packed weights.
// blockIdx.x = plane group (XCD selector). blockIdx.y = chunk.
// ---------------------------------------------------------------------------
template<int NS>
__device__ __forceinline__ void proj_body(
    const float* const* prmv, const unsigned int* __restrict__ imgP,
    float* const* p8v, unsigned int* pl)
{
    const int g     = blockIdx.x;          // 16 plane groups (XCD selector)
    const int chunk = blockIdx.y;          // 32 chunks x 2048 LORs
    const int tid   = threadIdx.x;
    const int lor0  = chunk * 2048 + tid;
    const float k0  = (float)(g * KG);

    float tA[2 * NS], uA[2 * NS], vA[2 * NS], dtA[2 * NS], duA[2 * NS], dvA[2 * NS], sA[2 * NS];
#pragma unroll
    for (int s = 0; s < 2 * NS; ++s) {
        const float* prm = prmv[s >> 1];
        const int lor = lor0 + (s & 1) * 1024;
        const float4* p4 = (const float4*)(prm + (size_t)lor * PRM_STRIDE);
        const float4 a = p4[0];
        const float4 b = p4[1];
        tA[s] = fmaf(k0, b.y, b.x);  dtA[s] = b.y;
        uA[s] = fmaf(k0, a.y, a.x);  duA[s] = a.y;
        vA[s] = fmaf(k0, a.w, a.z);  dvA[s] = a.w;
        sA[s] = 0.0f;
    }

    /* prologue: prefetch stage 0 into registers */
    uint4 pf0, pf1;
    {
        const uint4* src = (const uint4*)(imgP + (g * KG) * (NG * 64));
        pf0 = src[tid];
        pf1 = src[tid + 1024];
    }

    for (int st = 0; st < KG; ++st) {
        __syncthreads();                       /* previous compute done */
        uint4* dst = (uint4*)pl;
        dst[tid]        = pf0;
        dst[tid + 1024] = pf1;
        __syncthreads();                       /* plane ready */
        if (st + 1 < KG) {                     /* issue next-stage loads NOW;
                                                  consumed after next barrier */
            const uint4* src = (const uint4*)(imgP + (g * KG + st + 1) * (NG * 64));
            pf0 = src[tid];
            pf1 = src[tid + 1024];
        }

        const float fst = (float)st;
#pragma unroll
        for (int s = 0; s < 2 * NS; ++s) {
            const float t = fmaf(fst, dtA[s], tA[s]);
            const float u = fmaf(fst, duA[s], uA[s]);
            const float v = fmaf(fst, dvA[s], vA[s]);
            const float fi = rintf(u);
            const float fj = rintf(v);
            const int i0 = (int)fi;
            const int j0 = (int)fj;
            const float mi = fi - u;
            const float mj = fj - v;
            const float ci = -C2L * mi,  cj = -C2L * mj;
            const float a0i = ci * mi,   a0j = cj * mj;
            const float gi = ci + ci,    gj = cj + cj;
            const float ki = a0i - C2L,  kj = a0j - C2L;
            const float exm = __builtin_amdgcn_exp2f(ki - gi);
            const float ex0 = __builtin_amdgcn_exp2f(a0i);
            const float exq = __builtin_amdgcn_exp2f(ki + gi);
            const float eym = __builtin_amdgcn_exp2f(kj - gj);
            const float ey0 = __builtin_amdgcn_exp2f(a0j);
            const float eyq = __builtin_amdgcn_exp2f(kj + gj);

            /* window cols [j0-1, j0+1] live in words w,w+1; weight layout
               depends on j0 parity (odd: A=(eym,ey0) B=(eyq,0);
               even: A=(0,eym) B=(ey0,eyq)) */
            const _Float16 hm = (_Float16)eym, h0 = (_Float16)ey0,
                           hq = (_Float16)eyq, hz = (_Float16)0.0f;
            const bool odd = (j0 & 1) != 0;
            h2v wLo, wHi;
            wLo.x = odd ? hm : hz;  wLo.y = odd ? h0 : hm;
            wHi.x = odd ? hq : h0;  wHi.y = odd ? hz : hq;

            const int w  = min(max((j0 - 1) >> 1, 0), 62);
            const int ib = min(max(i0 - 1, 0), 125);

            const float exv[3] = {exm, ex0, exq};
            float acc = 0.0f;
#pragma unroll
            for (int a = 0; a < 3; ++a) {
                const int rowb = (ib + a) << 6;
                const unsigned Aw = pl[rowb + w];
                const unsigned Bw = pl[rowb + w + 1];
                float rd = fdot2w(Bw, wHi, 0.0f);
                rd = fdot2w(Aw, wLo, rd);
                acc = fmaf(exv[a], rd, acc);
            }
            const bool tin = (t >= 0.0f) && (t <= 1.0f);
            sA[s] += tin ? acc : 0.0f;
        }
    }
#pragma unroll
    for (int s = 0; s < NS; ++s) {
        p8v[s][g * NLOR + lor0]        = sA[2 * s];
        p8v[s][g * NLOR + lor0 + 1024] = sA[2 * s + 1];
    }
}

// blockIdx.z==0: z+y streams on imgPz; ==1: x stream on imgPx.
__global__ __launch_bounds__(1024, 8)
void proj_all(const float* __restrict__ prmz, const float* __restrict__ prmy,
              const float* __restrict__ prmx,
              const unsigned int* __restrict__ imgPz, const unsigned int* __restrict__ imgPx,
              float* __restrict__ p8z, float* __restrict__ p8y,
              float* __restrict__ p8x)
{
    __shared__ unsigned int pl[NG * 64];     /* 32 KB: plane as half2 pairs */
    if (blockIdx.z == 0) {
        const float* prmv[2] = {prmz, prmy};
        float* p8v[2] = {p8z, p8y};
        proj_body<2>(prmv, imgPz, p8v, pl);
    } else {
        const float* prmv[1] = {prmx};
        float* p8v[1] = {p8x};
        proj_body<1>(prmv, imgPx, p8v, pl);
    }
}

// ---------------------------------------------------------------------------
// cf for all three passes in one dispatch (blockIdx.y selects the pass).
// Stores cf PRE-SCALED by 2^23 into slot 6 (saves a mul per bp deposit).
// ---------------------------------------------------------------------------
__global__ __launch_bounds__(256)
void reduce_cf3(const float* __restrict__ zl, const float* __restrict__ yl,
                const float* __restrict__ xl,
                const float* __restrict__ p8z, const float* __restrict__ p8y,
                const float* __restrict__ p8x,
                float* __restrict__ prmz, float* __restrict__ prmy,
                float* __restrict__ prmx)
{
    const int which = blockIdx.y;
    const float* lors  = (which == 0) ? zl  : (which == 1) ? yl  : xl;
    const float* part8 = (which == 0) ? p8z : (which == 1) ? p8y : p8x;
    float*       prm   = (which == 0) ? prmz : (which == 1) ? prmy : prmx;

    const int lor = blockIdx.x * 256 + threadIdx.x;
    float s = 0.0f;
#pragma unroll
    for (int g = 0; g < NKG; ++g) s += part8[g * NLOR + lor];

    const float p1x = lors[0 * NLOR + lor];
    const float p1y = lors[1 * NLOR + lor];
    const float p1z = lors[2 * NLOR + lor];
    const float dx  = lors[3 * NLOR + lor] - p1x;
    const float dy  = lors[4 * NLOR + lor] - p1y;
    const float dz0 = lors[5 * NLOR + lor] - p1z;
    const float L = sqrtf(dx * dx + dy * dy + dz0 * dz0);
    const float adz = fmaxf(fabsf(dz0), 1e-6f);
    const float dl = VOX * L / adz;
    prm[(size_t)lor * PRM_STRIDE + 6] = (dl / (s * dl + 1e-8f)) * FPSCALE;
}

// ---------------------------------------------------------------------------
// bp deposit, op-minimized: exp2-domain weight recurrence, float-domain med3
// clamp + single fma address, select instead of branch, pre-scaled cf.
// u32 fixed-point LDS atomics (fp32 LDS atomics ~10x slower on gfx950).
// ---------------------------------------------------------------------------
__device__ __forceinline__ void bp_deposit(const float* __restrict__ prm,
    int lor, float fk, unsigned int* __restrict__ pl)
{
    const float4* p4 = (const float4*)(prm + (size_t)lor * PRM_STRIDE);
    const float4 a = p4[0];
    const float4 b = p4[1];
    const float t = fmaf(fk, b.y, b.x);
    const float u = fmaf(fk, a.y, a.x);
    const float v = fmaf(fk, a.w, a.z);
    const float fi = rintf(u);
    const float fj = rintf(v);
    const float cfs = ((t >= 0.0f) && (t <= 1.0f)) ? b.z : 0.0f;  /* cf*2^23 */

    const float mi = fi - u;
    const float mj = fj - v;
    const float ci = -C2L * mi,  cj = -C2L * mj;
    const float a0i = ci * mi,   a0j = cj * mj;
    const float gi = ci + ci,    gj = cj + cj;
    const float ki = a0i - C2L,  kj = a0j - C2L;

    const float ex0 = __builtin_amdgcn_exp2f(a0i) * cfs;
    const float exm = __builtin_amdgcn_exp2f(ki - gi) * cfs;
    const float exq = __builtin_amdgcn_exp2f(ki + gi) * cfs;
    const float ey0 = __builtin_amdgcn_exp2f(a0j);
    const float eym = __builtin_amdgcn_exp2f(kj - gj);
    const float eyq = __builtin_amdgcn_exp2f(kj + gj);

    /* clamp in float, one fma -> flat index; 9 targets = imm ds offsets */
    const float fib = __builtin_amdgcn_fmed3f(fi, 1.0f, 126.0f);
    const float fjb = __builtin_amdgcn_fmed3f(fj, 1.0f, 126.0f);
    const int idx = (int)fmaf(fib, (float)PLP, fjb) - (PLP + 1);
    unsigned int* base = pl + idx;

    const float exv[3] = {exm, ex0, exq};
#pragma unroll
    for (int aa = 0; aa < 3; ++aa) {
        unsigned int* row = base + aa * PLP;
        atomicAdd(row + 0, (unsigned int)(exv[aa] * eym));
        atomicAdd(row + 1, (unsigned int)(exv[aa] * ey0));
        atomicAdd(row + 2, (unsigned int)(exv[aa] * eyq));
    }
}

// ---------------------------------------------------------------------------
// All backprojection in one launch. blockIdx.y==0: z+y -> bpA; ==1: x -> bpB.
// Writes planes TRANSPOSED: bpA = A'[s][z][y][x], bpB = B'[s][y][x][z].
// ---------------------------------------------------------------------------
__global__ __launch_bounds__(1024)
void bp_all(const float* __restrict__ prmz, const float* __restrict__ prmy,
            const float* __restrict__ prmx,
            float* __restrict__ bpA, float* __restrict__ bpB)
{
    __shared__ unsigned int pl[NG * PLP];      /* 64.5 KB padded u32 plane */
    const int k   = blockIdx.x >> 1;
    const int sub = blockIdx.x & 1;
    const int tid = threadIdx.x;

    for (int i = tid; i < NG * PLP; i += 1024) pl[i] = 0u;
    __syncthreads();

    const float fk = (float)k;
    const int lo = sub * (NLOR / NSUB);
    constexpr int NIT = (NLOR / NSUB) / 1024;   /* 32 */
    float* bpsub;
    if (blockIdx.y == 0) {
#pragma unroll 2
        for (int it = 0; it < NIT; ++it) {
            const int lor = lo + tid + it * 1024;
            bp_deposit(prmz, lor, fk, pl);
            bp_deposit(prmy, lor, fk, pl);
        }
        bpsub = bpA;
    } else {
#pragma unroll 4
        for (int it = 0; it < NIT; ++it)
            bp_deposit(prmx, lo + tid + it * 1024, fk, pl);
        bpsub = bpB;
    }
    __syncthreads();

    /* transposed writeout: dst[q*128 + p] = pl[p][q]; LDS lanes stride PLP
       (conflict-free), global contiguous */
    float* dst = bpsub + ((size_t)(sub * NG + k)) * PLANE;
    for (int idx = tid; idx < PLANE; idx += 1024)
        dst[idx] = (float)pl[(idx & 127) * PLP + (idx >> 7)] * INVFPSCALE;
}

// ---------------------------------------------------------------------------
// Single-pass finalize: out[x][y][z] = img/eff * (sum_s A'[s][z][y][x]
//                                              +  sum_s B'[s][y][x][z]).
// ---------------------------------------------------------------------------
__global__ __launch_bounds__(256)
void finalize_out(const float* __restrict__ bpA, const float* __restrict__ bpB,
                  const float* __restrict__ img, const float* __restrict__ eff,
                  float* __restrict__ out)
{
    __shared__ float tA[32][33];
    const int b  = blockIdx.z;              /* y */
    const int x0 = blockIdx.x * 32;
    const int z0 = blockIdx.y * 32;
    const int tx = threadIdx.x, ty = threadIdx.y;
    const int VOL = NG * PLANE;

#pragma unroll
    for (int m = 0; m < 4; ++m) {
        const int z = z0 + ty + 8 * m;
        const int a = z * PLANE + b * NG + (x0 + tx);
        tA[ty + 8 * m][tx] = bpA[a] + bpA[a + VOL];
    }
    __syncthreads();
#pragma unroll
    for (int m = 0; m < 4; ++m) {
        const int x  = x0 + ty + 8 * m;
        const int o  = x * PLANE + b * NG + (z0 + tx);
        const int bb = b * PLANE + x * NG + (z0 + tx);
        const float v = tA[tx][ty + 8 * m] + bpB[bb] + bpB[bb + VOL];
        out[o] = img[o] / (eff[o] + 1e-8f) * v;
    }
}

extern "C" void kernel_launch(void* const* d_in, const int* in_sizes, int n_in,
                              void* d_out, int out_size, void* d_ws, size_t ws_size,
                              hipStream_t stream) {
    const float* image = (const float*)d_in[0];
    const float* eff   = (const float*)d_in[1];
    const float* xl    = (const float*)d_in[2];
    const float* yl    = (const float*)d_in[3];
    const float* zl    = (const float*)d_in[4];
    float* out = (float*)d_out;

    char* ws = (char*)d_ws;
    __half* imgPz = (__half*)(ws);                       //  4 MB [z][x][y] half
    __half* imgPx = (__half*)(ws + (size_t)( 4 << 20));  //  4 MB [y][z][x] half
    float* bpA    = (float*)(ws + (size_t)( 8 << 20));   // 16 MB A'[s][z][y][x]
    float* bpB    = (float*)(ws + (size_t)(24 << 20));   // 16 MB B'[s][y][x][z]
    float* p8z    = (float*)(ws + (size_t)(40 << 20));   //  4 MB
    float* p8y    = (float*)(ws + (size_t)(44 << 20));   //  4 MB
    float* p8x    = (float*)(ws + (size_t)(48 << 20));   //  4 MB
    float* prmz   = (float*)(ws + (size_t)(52 << 20));   //  2 MB per-LOR params
    float* prmy   = (float*)(ws + (size_t)(54 << 20));   //  2 MB
    float* prmx   = (float*)(ws + (size_t)(56 << 20));   //  2 MB

    const dim3 tb(32, 8);

    // 1) image permutes + LOR param prep, one launch (z slices 256..303 = prep)
    perm_img2<<<dim3(4, 4, 304), tb, 0, stream>>>(image, imgPz, imgPx,
        zl, yl, xl, prmz, prmy, prmx);
    // 2) all projections; grid.x = plane group for XCD L2 locality
    proj_all<<<dim3(16, 32, 2), 1024, 0, stream>>>(prmz, prmy, prmx,
        (const unsigned int*)imgPz, (const unsigned int*)imgPx, p8z, p8y, p8x);
    // 3) correction factors (pre-scaled by 2^23) -> params slot 6
    reduce_cf3<<<dim3(256, 3), 256, 0, stream>>>(zl, yl, xl, p8z, p8y, p8x, prmz, prmy, prmx);
    // 4) all backprojection (z+y -> bpA | x -> bpB), transposed plane writeout
    bp_all<<<dim3(128 * NSUB, 2), 1024, 0, stream>>>(prmz, prmy, prmx, bpA, bpB);
    // 5) fused gather + finalize (single pass over out)
    finalize_out<<<dim3(4, 4, 128), tb, 0, stream>>>(bpA, bpB, image, eff, out);
}